// Round 2
// baseline (132.622 us; speedup 1.0000x reference)
//
#include <hip/hip_runtime.h>
#include <hip/hip_bf16.h>

#define NS_ 4096
#define M_  8192
#define D_  256
#define TEMP 0.07f
// exp(sim/T) = exp2(sim * log2(e)/T)
#define EXP_SCALE (1.4426950408889634f / 0.07f)
#define LN2 0.6931471805599453f

typedef short bf16x8 __attribute__((ext_vector_type(8)));
typedef float f32x4  __attribute__((ext_vector_type(4)));
typedef unsigned short ushortx4 __attribute__((ext_vector_type(4)));

static __device__ inline unsigned short f2bf(float x) {
    // round-to-nearest-even f32 -> bf16 (inputs already cleaned, no NaN path needed)
    unsigned u = __float_as_uint(x);
    u += 0x7fffu + ((u >> 16) & 1u);
    return (unsigned short)(u >> 16);
}

static __device__ inline float cleanf(float v) {
    return __builtin_isfinite(v) ? v : 0.0f;
}

// ---------------- Kernel 1: clean + L2-normalize rows, emit bf16 F and fp32 positives ----
// grid = NS_, block = 64 (one wave per paired row)
__global__ __launch_bounds__(64) void knorm(const float* __restrict__ z1,
                                            const float* __restrict__ z2,
                                            short* __restrict__ F,
                                            float* __restrict__ pos) {
    const int i = blockIdx.x;     // 0..NS-1
    const int t = threadIdx.x;    // 0..63, 4 elements each
    const float4* p1 = (const float4*)(z1 + (size_t)i * D_);
    const float4* p2 = (const float4*)(z2 + (size_t)i * D_);
    float4 a = p1[t], b = p2[t];
    a.x = cleanf(a.x); a.y = cleanf(a.y); a.z = cleanf(a.z); a.w = cleanf(a.w);
    b.x = cleanf(b.x); b.y = cleanf(b.y); b.z = cleanf(b.z); b.w = cleanf(b.w);

    float s1 = a.x*a.x + a.y*a.y + a.z*a.z + a.w*a.w;
    float s2 = b.x*b.x + b.y*b.y + b.z*b.z + b.w*b.w;
    float dp = a.x*b.x + a.y*b.y + a.z*b.z + a.w*b.w;
    #pragma unroll
    for (int m = 1; m < 64; m <<= 1) {
        s1 += __shfl_xor(s1, m);
        s2 += __shfl_xor(s2, m);
        dp += __shfl_xor(dp, m);
    }
    const float inv1 = 1.0f / fmaxf(sqrtf(s1), 1e-12f);
    const float inv2 = 1.0f / fmaxf(sqrtf(s2), 1e-12f);

    ushortx4 o1, o2;
    o1.x = f2bf(a.x * inv1); o1.y = f2bf(a.y * inv1); o1.z = f2bf(a.z * inv1); o1.w = f2bf(a.w * inv1);
    o2.x = f2bf(b.x * inv2); o2.y = f2bf(b.y * inv2); o2.z = f2bf(b.z * inv2); o2.w = f2bf(b.w * inv2);
    ((ushortx4*)(F + (size_t)i * D_))[t]          = o1;
    ((ushortx4*)(F + (size_t)(i + NS_) * D_))[t]  = o2;

    if (t == 0) pos[i] = dp * inv1 * inv2;   // exact fp32 positive sim
}

// ---------------- Kernel 2: fused sim-GEMM + per-row sum(exp(sim/T)), diagonal masked ----
// grid = 512 : blockIdx = rtile*4 + cquarter. 64 rows x 2048 cols per block.
// A frags held in registers (full K=256); B tiles (64 cols x 256 K) staged via LDS.
#define BLDS_STRIDE 264   // 256 + 8 bf16 pad -> row stride 528B, banks spread
__global__ __launch_bounds__(256) void kgemm(const short* __restrict__ F,
                                             float* __restrict__ denom) {
    __shared__ short Bl[64 * BLDS_STRIDE];

    const int rtile = blockIdx.x >> 2;
    const int cq    = blockIdx.x & 3;
    const int R0 = rtile * 64;
    const int C0 = cq * 2048;

    const int tid  = threadIdx.x;
    const int lane = tid & 63;
    const int wave = tid >> 6;
    const int c16  = lane & 15;
    const int quad = lane >> 4;

    // Load A fragments: rows R0 + wave*16 + c16, k = ks*32 + quad*8 + [0..7]
    bf16x8 afrag[8];
    {
        const short* ap = F + (size_t)(R0 + wave * 16 + c16) * D_ + quad * 8;
        #pragma unroll
        for (int ks = 0; ks < 8; ++ks)
            afrag[ks] = *(const bf16x8*)(ap + ks * 32);
    }

    float accexp[4] = {0.f, 0.f, 0.f, 0.f};
    const int grow0 = R0 + wave * 16 + quad * 4;

    for (int it = 0; it < 32; ++it) {
        __syncthreads();
        // stage B tile: 64 rows x 512B = 2048 x 16B chunks, 8 chunks per thread,
        // coalesced 16B per lane
        {
            const uint4* src = (const uint4*)(F + (size_t)(C0 + it * 64) * D_);
            #pragma unroll
            for (int r2 = 0; r2 < 8; ++r2) {
                int c   = tid + r2 * 256;      // chunk 0..2047
                int row = c >> 5;              // 32 x 16B chunks per row
                int k   = c & 31;
                *(uint4*)(&Bl[row * BLDS_STRIDE + k * 8]) = src[row * 32 + k];
            }
        }
        __syncthreads();

        #pragma unroll
        for (int sub = 0; sub < 4; ++sub) {
            const short* bp = &Bl[(sub * 16 + c16) * BLDS_STRIDE + quad * 8];
            f32x4 acc = {0.f, 0.f, 0.f, 0.f};
            #pragma unroll
            for (int ks = 0; ks < 8; ++ks) {
                bf16x8 bfrag = *(const bf16x8*)(bp + ks * 32);
                acc = __builtin_amdgcn_mfma_f32_16x16x32_bf16(afrag[ks], bfrag, acc, 0, 0, 0);
            }
            const int gcol = C0 + it * 64 + sub * 16 + c16;
            #pragma unroll
            for (int r = 0; r < 4; ++r) {
                float e = __builtin_amdgcn_exp2f(acc[r] * EXP_SCALE);
                if (grow0 + r == gcol) e = 0.0f;   // mask diagonal
                accexp[r] += e;
            }
        }
    }

    // reduce each row-sum across the 16 lanes of the quad, one atomic per row
    #pragma unroll
    for (int r = 0; r < 4; ++r) {
        float v = accexp[r];
        v += __shfl_xor(v, 1);
        v += __shfl_xor(v, 2);
        v += __shfl_xor(v, 4);
        v += __shfl_xor(v, 8);
        if (c16 == 0) atomicAdd(&denom[grow0 + r], v);
    }
}

// ---------------- Kernel 3: loss = mean(log(denom)) - 2*sum(pos)/(T*M) ------------------
__global__ __launch_bounds__(256) void kfinal(const float* __restrict__ denom,
                                              const float* __restrict__ pos,
                                              float* __restrict__ out) {
    const int tid = threadIdx.x;
    float sl = 0.f, sp = 0.f;
    for (int i = tid; i < M_; i += 256)
        sl += __builtin_amdgcn_logf(denom[i]) * LN2;   // v_log_f32 is log2
    for (int i = tid; i < NS_; i += 256)
        sp += pos[i];
    #pragma unroll
    for (int m = 1; m < 64; m <<= 1) {
        sl += __shfl_xor(sl, m);
        sp += __shfl_xor(sp, m);
    }
    __shared__ float redL[4], redP[4];
    const int wave = tid >> 6, lane = tid & 63;
    if (lane == 0) { redL[wave] = sl; redP[wave] = sp; }
    __syncthreads();
    if (tid == 0) {
        float SL = redL[0] + redL[1] + redL[2] + redL[3];
        float SP = redP[0] + redP[1] + redP[2] + redP[3];
        out[0] = (SL - 2.0f * SP / TEMP) / (float)M_;
    }
}

extern "C" void kernel_launch(void* const* d_in, const int* in_sizes, int n_in,
                              void* d_out, int out_size, void* d_ws, size_t ws_size,
                              hipStream_t stream) {
    const float* z1 = (const float*)d_in[0];
    const float* z2 = (const float*)d_in[1];

    short* F     = (short*)d_ws;                                   // 8192*256*2 = 4 MB
    float* denom = (float*)((char*)d_ws + (size_t)M_ * D_ * 2);    // 32 KB
    float* pos   = denom + M_;                                     // 16 KB
    float* out   = (float*)d_out;

    hipMemsetAsync(denom, 0, M_ * sizeof(float), stream);
    knorm<<<NS_, 64, 0, stream>>>(z1, z2, F, pos);
    kgemm<<<512, 256, 0, stream>>>(F, denom);
    kfinal<<<1, 256, 0, stream>>>(denom, pos, out);
}